// Round 3
// baseline (140.144 us; speedup 1.0000x reference)
//
#include <hip/hip_runtime.h>
#include <math.h>

// For each edge m: p[k] = dot(z[src][k*32:(k+1)*32], z[trg][k*32:(k+1)*32]),
// out[m] = sigmoid(max_k p[k]).
//
// One 64-lane wave handles E=4 consecutive edges to build memory-level
// parallelism: all 8 row gathers (float4/lane, perfectly coalesced 1 KiB/row)
// are issued back-to-back before any reduction consumes them, and the four
// 6-deep shfl reduction chains are independent (ILP).
//
// edge_index arrives as int32 (harness converts integer inputs), shape (2, M).

#define EDGES_PER_WAVE 4

__global__ __launch_bounds__(256) void max_deco_kernel(
    const float* __restrict__ z,
    const int* __restrict__ ei,   // (2, M) int32
    float* __restrict__ out,
    int m_total)
{
    const int wave = blockIdx.x * (blockDim.x >> 6) + (threadIdx.x >> 6);
    const int lane = threadIdx.x & 63;
    const int base = wave * EDGES_PER_WAVE;
    if (base >= m_total) return;

    // Wave-uniform index loads (compiler emits scalar loads).
    int i0[EDGES_PER_WAVE], i1[EDGES_PER_WAVE];
#pragma unroll
    for (int e = 0; e < EDGES_PER_WAVE; ++e) {
        const int m = base + e;
        const int mm = (m < m_total) ? m : base;   // clamp tail to a valid edge
        i0[e] = ei[mm];
        i1[e] = ei[mm + m_total];
    }

    // Issue all row gathers before consuming any (8 float4 loads in flight).
    float4 a[EDGES_PER_WAVE], b[EDGES_PER_WAVE];
#pragma unroll
    for (int e = 0; e < EDGES_PER_WAVE; ++e) {
        a[e] = ((const float4*)(z + (size_t)i0[e] * 256))[lane];
        b[e] = ((const float4*)(z + (size_t)i1[e] * 256))[lane];
    }

    // Four independent reduction chains.
#pragma unroll
    for (int e = 0; e < EDGES_PER_WAVE; ++e) {
        float d = a[e].x * b[e].x + a[e].y * b[e].y
                + a[e].z * b[e].z + a[e].w * b[e].w;

        // sum within the 8-lane capsule group (capsule = 32 contiguous floats)
        d += __shfl_xor(d, 1);
        d += __shfl_xor(d, 2);
        d += __shfl_xor(d, 4);

        // max across the 8 capsules
        d = fmaxf(d, __shfl_xor(d, 8));
        d = fmaxf(d, __shfl_xor(d, 16));
        d = fmaxf(d, __shfl_xor(d, 32));

        if (lane == 0 && base + e < m_total) {
            out[base + e] = 1.0f / (1.0f + __expf(-d));
        }
    }
}

extern "C" void kernel_launch(void* const* d_in, const int* in_sizes, int n_in,
                              void* d_out, int out_size, void* d_ws, size_t ws_size,
                              hipStream_t stream) {
    const float* z = (const float*)d_in[0];
    const int* ei = (const int*)d_in[1];
    float* out = (float*)d_out;

    const int m_total = in_sizes[1] / 2;   // edge_index is (2, M)

    const int waves_per_block = 256 / 64;
    const int edges_per_block = waves_per_block * EDGES_PER_WAVE;  // 16
    const int grid = (m_total + edges_per_block - 1) / edges_per_block;

    max_deco_kernel<<<grid, 256, 0, stream>>>(z, ei, out, m_total);
}

// Round 4
// 93.237 us; speedup vs baseline: 1.5031x; 1.5031x over previous
//
#include <hip/hip_runtime.h>
#include <hip/hip_fp16.h>
#include <math.h>

typedef unsigned int uint;

// Round 4 design:
//   Pass 1: convert z (100k x 256 fp32, 102 MB) -> fp16 in d_ws (51 MB).
//   Pass 2: per edge, ONE fused gather: lanes 0-31 load the 512B src row
//           (uint4 = 8 halves/lane), lanes 32-63 load the trg row.
//           shfl_xor(32) pairs src/trg chunks; 8-half dot per lane;
//           capsule = 4 lanes (xor 1,2 sum), max over 8 capsules (xor 4,8,16).
// Halves both gather bytes and gather request count vs the fp32 kernel.
// Conversion runs every call (deterministic, idempotent) — no cross-call state.

__global__ __launch_bounds__(256) void cvt_f32_f16(
    const float4* __restrict__ zin, uint4* __restrict__ zh, int n8)
{
    int t = blockIdx.x * blockDim.x + threadIdx.x;
    if (t >= n8) return;
    float4 v0 = zin[2 * t];
    float4 v1 = zin[2 * t + 1];
    __half2 h0 = __floats2half2_rn(v0.x, v0.y);
    __half2 h1 = __floats2half2_rn(v0.z, v0.w);
    __half2 h2 = __floats2half2_rn(v1.x, v1.y);
    __half2 h3 = __floats2half2_rn(v1.z, v1.w);
    uint4 o;
    __builtin_memcpy(&o.x, &h0, 4);
    __builtin_memcpy(&o.y, &h1, 4);
    __builtin_memcpy(&o.z, &h2, 4);
    __builtin_memcpy(&o.w, &h3, 4);
    zh[t] = o;
}

#define EPW 4  // edges per wave

__global__ __launch_bounds__(256) void max_deco_h_kernel(
    const unsigned short* __restrict__ zh,  // (100k, 256) fp16
    const int* __restrict__ ei,             // (2, M) int32
    float* __restrict__ out,
    int m_total)
{
    const int wave = blockIdx.x * (blockDim.x >> 6) + (threadIdx.x >> 6);
    const int lane = threadIdx.x & 63;
    const int base = wave * EPW;
    if (base >= m_total) return;

    const int hl = lane & 31;
    const bool trgside = lane >= 32;

    int rows[EPW];
#pragma unroll
    for (int e = 0; e < EPW; ++e) {
        int m = base + e;
        m = (m < m_total) ? m : base;          // clamp tail
        const int r0 = ei[m];                  // scalar (wave-uniform) loads
        const int r1 = ei[m + m_total];
        rows[e] = trgside ? r1 : r0;
    }

    // One 16B load per lane per edge: lanes 0-31 = src row, 32-63 = trg row.
    uint4 va[EPW];
#pragma unroll
    for (int e = 0; e < EPW; ++e)
        va[e] = ((const uint4*)(zh + (size_t)rows[e] * 256))[hl];

#pragma unroll
    for (int e = 0; e < EPW; ++e) {
        uint4 vb;
        vb.x = (uint)__shfl_xor((int)va[e].x, 32);
        vb.y = (uint)__shfl_xor((int)va[e].y, 32);
        vb.z = (uint)__shfl_xor((int)va[e].z, 32);
        vb.w = (uint)__shfl_xor((int)va[e].w, 32);

        const uint ua[4] = {va[e].x, va[e].y, va[e].z, va[e].w};
        const uint ub[4] = {vb.x, vb.y, vb.z, vb.w};
        float d = 0.0f;
#pragma unroll
        for (int q = 0; q < 4; ++q) {
            __half2 ha, hb;
            __builtin_memcpy(&ha, &ua[q], 4);
            __builtin_memcpy(&hb, &ub[q], 4);
            float2 fa = __half22float2(ha);
            float2 fb = __half22float2(hb);
            d = fmaf(fa.x, fb.x, d);
            d = fmaf(fa.y, fb.y, d);
        }

        // capsule k = elements 32k..32k+31 = lanes 4k..4k+3 (8 halves/lane)
        d += __shfl_xor(d, 1);
        d += __shfl_xor(d, 2);
        // max across the 8 capsules
        d = fmaxf(d, __shfl_xor(d, 4));
        d = fmaxf(d, __shfl_xor(d, 8));
        d = fmaxf(d, __shfl_xor(d, 16));

        if (lane == 0) {
            const int m = base + e;
            if (m < m_total) out[m] = 1.0f / (1.0f + __expf(-d));
        }
    }
}

// fp32 fallback (proven round-2 kernel) in case ws_size is too small.
__global__ __launch_bounds__(256) void max_deco_f32_kernel(
    const float* __restrict__ z,
    const int* __restrict__ ei,
    float* __restrict__ out,
    int m_total)
{
    const int wave = blockIdx.x * (blockDim.x >> 6) + (threadIdx.x >> 6);
    const int lane = threadIdx.x & 63;
    if (wave >= m_total) return;

    const int i0 = ei[wave];
    const int i1 = ei[wave + m_total];
    float4 a = ((const float4*)(z + (size_t)i0 * 256))[lane];
    float4 b = ((const float4*)(z + (size_t)i1 * 256))[lane];
    float d = a.x * b.x + a.y * b.y + a.z * b.z + a.w * b.w;
    d += __shfl_xor(d, 1);
    d += __shfl_xor(d, 2);
    d += __shfl_xor(d, 4);
    d = fmaxf(d, __shfl_xor(d, 8));
    d = fmaxf(d, __shfl_xor(d, 16));
    d = fmaxf(d, __shfl_xor(d, 32));
    if (lane == 0) out[wave] = 1.0f / (1.0f + __expf(-d));
}

extern "C" void kernel_launch(void* const* d_in, const int* in_sizes, int n_in,
                              void* d_out, int out_size, void* d_ws, size_t ws_size,
                              hipStream_t stream) {
    const float* z = (const float*)d_in[0];
    const int* ei = (const int*)d_in[1];
    float* out = (float*)d_out;

    const int n_z = in_sizes[0];           // 100000*256
    const int m_total = in_sizes[1] / 2;   // edge_index is (2, M)

    const size_t need = (size_t)n_z * 2;   // fp16 copy of z
    if (ws_size >= need) {
        unsigned short* zh = (unsigned short*)d_ws;

        const int n8 = n_z / 8;            // 8 floats per cvt thread
        cvt_f32_f16<<<(n8 + 255) / 256, 256, 0, stream>>>(
            (const float4*)z, (uint4*)zh, n8);

        const int waves_per_block = 256 / 64;
        const int edges_per_block = waves_per_block * EPW;  // 16
        const int grid = (m_total + edges_per_block - 1) / edges_per_block;
        max_deco_h_kernel<<<grid, 256, 0, stream>>>(zh, ei, out, m_total);
    } else {
        const int grid = (m_total + 3) / 4;
        max_deco_f32_kernel<<<grid, 256, 0, stream>>>(z, ei, out, m_total);
    }
}